// Round 2
// baseline (413.863 us; speedup 1.0000x reference)
//
#include <hip/hip_runtime.h>
#include <hip/hip_bf16.h>
#include <cstdint>

#define B_   4
#define T_   2048
#define C_   1024
#define H_   16
#define D_   64
#define TC3  3072
#define M_   (B_ * T_)   // 8192

typedef short  bf16x8 __attribute__((ext_vector_type(8)));
typedef float  f32x4  __attribute__((ext_vector_type(4)));

#define AS1(p) ((const __attribute__((address_space(1))) void*)(p))
#define AS3(p) ((__attribute__((address_space(3))) void*)(p))

__device__ inline unsigned short f2bf(float f) {
    union { float f; unsigned int i; } x; x.f = f;
    return (unsigned short)((x.i + 0x7fffu + ((x.i >> 16) & 1u)) >> 16);
}

// ---------------- cast f32 -> bf16, 8 elements/thread ----------------
__global__ void cast_f32_bf16(const float* __restrict__ in,
                              unsigned short* __restrict__ out) {
    const size_t i = ((size_t)blockIdx.x * blockDim.x + threadIdx.x) * 8;
    f32x4 a = *(const f32x4*)(in + i);
    f32x4 b = *(const f32x4*)(in + i + 4);
    bf16x8 o;
#pragma unroll
    for (int j = 0; j < 4; ++j) { o[j] = (short)f2bf(a[j]); o[4 + j] = (short)f2bf(b[j]); }
    *(bf16x8*)(out + i) = o;
}

// ---------------- transpose + cast: in[R][C] f32 -> out[C][R] bf16 ----------------
__global__ void transpose_cast(const float* __restrict__ in,
                               unsigned short* __restrict__ out, int R, int C) {
    __shared__ unsigned short tile[32][33];
    const int bc = blockIdx.x * 32, br = blockIdx.y * 32;
    const int tx = threadIdx.x & 31, ty = threadIdx.x >> 5;
#pragma unroll
    for (int i = 0; i < 4; ++i) {
        int r = ty + i * 8;
        tile[r][tx] = f2bf(in[(size_t)(br + r) * C + bc + tx]);
    }
    __syncthreads();
#pragma unroll
    for (int i = 0; i < 4; ++i) {
        int r = ty + i * 8;
        out[(size_t)(bc + r) * R + br + tx] = tile[tx][r];
    }
}

// ------------- GEMM: C[M][N] = A[M][K] * Bt[N][K]^T + bias[N] (bf16 in, f32 acc) -------------
// 128x128 tile, BK=32, 4 waves (2x2), 4x4 16x16x32 MFMA per wave. m97-style.
template <bool OUTF32>
__global__ __launch_bounds__(256, 2) void gemm_bt_bias(
    const unsigned short* __restrict__ A, const unsigned short* __restrict__ Bt,
    const float* __restrict__ bias, void* __restrict__ Cout,
    int M, int N, int K) {
    __shared__ unsigned short As[128 * 32];
    __shared__ unsigned short Bs[128 * 32];
    const int tid = threadIdx.x;
    const int wave = tid >> 6, lane = tid & 63;
    const int m0 = blockIdx.x * 128, n0 = blockIdx.y * 128;
    const int wr = (wave >> 1) * 64, wc = (wave & 1) * 64;

    f32x4 acc[4][4] = {};

    const int srow = (lane >> 2);
    const int scol = (lane & 3) * 8;

    for (int k0 = 0; k0 < K; k0 += 32) {
#pragma unroll
        for (int j = 0; j < 2; ++j) {
            const int chunk = wave * 2 + j;
            const int row = chunk * 16 + srow;
            __builtin_amdgcn_global_load_lds(
                AS1(A + (size_t)(m0 + row) * K + k0 + scol),
                AS3(As + chunk * 512), 16, 0, 0);
            __builtin_amdgcn_global_load_lds(
                AS1(Bt + (size_t)(n0 + row) * K + k0 + scol),
                AS3(Bs + chunk * 512), 16, 0, 0);
        }
        __syncthreads();
        bf16x8 a[4], b[4];
#pragma unroll
        for (int i = 0; i < 4; ++i)
            a[i] = *(const bf16x8*)&As[(wr + i * 16 + (lane & 15)) * 32 + (lane >> 4) * 8];
#pragma unroll
        for (int i = 0; i < 4; ++i)
            b[i] = *(const bf16x8*)&Bs[(wc + i * 16 + (lane & 15)) * 32 + (lane >> 4) * 8];
#pragma unroll
        for (int i = 0; i < 4; ++i)
#pragma unroll
            for (int j = 0; j < 4; ++j)
                acc[i][j] = __builtin_amdgcn_mfma_f32_16x16x32_bf16(a[i], b[j], acc[i][j], 0, 0, 0);
        __syncthreads();
    }

#pragma unroll
    for (int i = 0; i < 4; ++i) {
        const int rowb = m0 + wr + i * 16 + (lane >> 4) * 4;
#pragma unroll
        for (int j = 0; j < 4; ++j) {
            const int col = n0 + wc + j * 16 + (lane & 15);
            const float bv = bias[col];
#pragma unroll
            for (int r = 0; r < 4; ++r) {
                const float v = acc[i][j][r] + bv;
                if (OUTF32)
                    ((float*)Cout)[(size_t)(rowb + r) * N + col] = v;
                else
                    ((unsigned short*)Cout)[(size_t)(rowb + r) * N + col] = f2bf(v);
            }
        }
    }
}

// ------------- causal flash attention -------------
// grid: (T/64, B*H). 4 waves, each owns 16 q-rows. KVBLK=64.
__global__ __launch_bounds__(256, 2) void attn_kernel(
    const unsigned short* __restrict__ QKV, unsigned short* __restrict__ Y) {
    __shared__ unsigned short Kl[64][72];
    __shared__ unsigned short Vt[64][72];
    __shared__ unsigned short Pl[4][16][72];

    const int tid = threadIdx.x, wave = tid >> 6, lane = tid & 63;
    const int qb = blockIdx.x * 64;
    const int bh = blockIdx.y;
    const int b = bh >> 4, h = bh & 15;
    const size_t rowbase = (size_t)b * T_ * TC3;
    const int q0 = qb + wave * 16;

    bf16x8 qf[2];
    {
        const unsigned short* p =
            QKV + rowbase + (size_t)(q0 + (lane & 15)) * TC3 + h * 64 + (lane >> 4) * 8;
        qf[0] = *(const bf16x8*)p;
        qf[1] = *(const bf16x8*)(p + 32);
    }

    float m_run[4], l_run[4];
    f32x4 o[4] = {};
#pragma unroll
    for (int r = 0; r < 4; ++r) { m_run[r] = -1e30f; l_run[r] = 0.f; }

    const int ntiles = blockIdx.x + 1;
    for (int t = 0; t < ntiles; ++t) {
        const int kv0 = t * 64;
        __syncthreads();
        for (int i = tid; i < 512; i += 256) {
            const int row = i >> 3, seg = i & 7;
            const unsigned short* src =
                QKV + rowbase + (size_t)(kv0 + row) * TC3 + C_ + h * 64 + seg * 8;
            *(bf16x8*)&Kl[row][seg * 8] = *(const bf16x8*)src;
            bf16x8 v = *(const bf16x8*)(src + C_);
#pragma unroll
            for (int jj = 0; jj < 8; ++jj)
                Vt[seg * 8 + jj][row] = (unsigned short)v[jj];
        }
        __syncthreads();

        f32x4 s[4];
#pragma unroll
        for (int kt = 0; kt < 4; ++kt) {
            bf16x8 kf0 = *(const bf16x8*)&Kl[kt * 16 + (lane & 15)][(lane >> 4) * 8];
            bf16x8 kf1 = *(const bf16x8*)&Kl[kt * 16 + (lane & 15)][32 + (lane >> 4) * 8];
            f32x4 acc = {};
            acc = __builtin_amdgcn_mfma_f32_16x16x32_bf16(qf[0], kf0, acc, 0, 0, 0);
            acc = __builtin_amdgcn_mfma_f32_16x16x32_bf16(qf[1], kf1, acc, 0, 0, 0);
            s[kt] = acc;
        }
#pragma unroll
        for (int kt = 0; kt < 4; ++kt) {
            const int kcol = kv0 + kt * 16 + (lane & 15);
#pragma unroll
            for (int r = 0; r < 4; ++r) {
                const int q = q0 + (lane >> 4) * 4 + r;
                const float v = s[kt][r] * 0.125f;
                s[kt][r] = (kcol <= q) ? v : -1e30f;
            }
        }
        float tmax[4];
#pragma unroll
        for (int r = 0; r < 4; ++r)
            tmax[r] = fmaxf(fmaxf(s[0][r], s[1][r]), fmaxf(s[2][r], s[3][r]));
#pragma unroll
        for (int msk = 1; msk < 16; msk <<= 1)
#pragma unroll
            for (int r = 0; r < 4; ++r)
                tmax[r] = fmaxf(tmax[r], __shfl_xor(tmax[r], msk, 64));

        float mnew[4], corr[4];
#pragma unroll
        for (int r = 0; r < 4; ++r) {
            mnew[r] = fmaxf(m_run[r], tmax[r]);
            corr[r] = __expf(m_run[r] - mnew[r]);
        }
        float tsum[4] = {0.f, 0.f, 0.f, 0.f};
#pragma unroll
        for (int kt = 0; kt < 4; ++kt)
#pragma unroll
            for (int r = 0; r < 4; ++r) {
                const float p = __expf(s[kt][r] - mnew[r]);
                s[kt][r] = p;
                tsum[r] += p;
            }
#pragma unroll
        for (int msk = 1; msk < 16; msk <<= 1)
#pragma unroll
            for (int r = 0; r < 4; ++r)
                tsum[r] += __shfl_xor(tsum[r], msk, 64);
#pragma unroll
        for (int r = 0; r < 4; ++r) {
            l_run[r] = l_run[r] * corr[r] + tsum[r];
            m_run[r] = mnew[r];
        }
#pragma unroll
        for (int dt = 0; dt < 4; ++dt)
#pragma unroll
            for (int r = 0; r < 4; ++r) o[dt][r] *= corr[r];

#pragma unroll
        for (int kt = 0; kt < 4; ++kt)
#pragma unroll
            for (int r = 0; r < 4; ++r)
                Pl[wave][(lane >> 4) * 4 + r][kt * 16 + (lane & 15)] = f2bf(s[kt][r]);
        __syncthreads();

        bf16x8 pf[2];
        pf[0] = *(const bf16x8*)&Pl[wave][lane & 15][(lane >> 4) * 8];
        pf[1] = *(const bf16x8*)&Pl[wave][lane & 15][32 + (lane >> 4) * 8];
#pragma unroll
        for (int dt = 0; dt < 4; ++dt) {
            bf16x8 vf0 = *(const bf16x8*)&Vt[dt * 16 + (lane & 15)][(lane >> 4) * 8];
            bf16x8 vf1 = *(const bf16x8*)&Vt[dt * 16 + (lane & 15)][32 + (lane >> 4) * 8];
            o[dt] = __builtin_amdgcn_mfma_f32_16x16x32_bf16(pf[0], vf0, o[dt], 0, 0, 0);
            o[dt] = __builtin_amdgcn_mfma_f32_16x16x32_bf16(pf[1], vf1, o[dt], 0, 0, 0);
        }
    }

#pragma unroll
    for (int dt = 0; dt < 4; ++dt)
#pragma unroll
        for (int r = 0; r < 4; ++r) {
            const int q = q0 + (lane >> 4) * 4 + r;
            const int d = dt * 16 + (lane & 15);
            Y[((size_t)b * T_ + q) * C_ + h * 64 + d] = f2bf(o[dt][r] / l_run[r]);
        }
}

extern "C" void kernel_launch(void* const* d_in, const int* in_sizes, int n_in,
                              void* d_out, int out_size, void* d_ws, size_t ws_size,
                              hipStream_t stream) {
    const float* x     = (const float*)d_in[0];
    const float* Wqkv  = (const float*)d_in[1];
    const float* bqkv  = (const float*)d_in[2];
    const float* Wproj = (const float*)d_in[3];
    const float* bproj = (const float*)d_in[4];
    float* out = (float*)d_out;

    char* ws = (char*)d_ws;
    unsigned short* qkv    = (unsigned short*)(ws);                          // 8192x3072 bf16 = 50331648 B
    unsigned short* yat    = (unsigned short*)(ws + 50331648);               // 8192x1024 bf16 = 16777216 B
    unsigned short* WqkvT  = (unsigned short*)(ws + 67108864);               // 3072x1024 bf16 =  6291456 B
    unsigned short* WprojT = (unsigned short*)(ws + 73400320);               // 1024x1024 bf16 =  2097152 B
    unsigned short* xb     = (unsigned short*)(ws + 75497472);               // 8192x1024 bf16 = 16777216 B

    // cast x to bf16
    cast_f32_bf16<<<dim3((M_ * C_) / (256 * 8)), dim3(256), 0, stream>>>(x, xb);
    // weight transposes + cast (so both GEMMs take B^T with contiguous K)
    transpose_cast<<<dim3(TC3 / 32, C_ / 32), dim3(256), 0, stream>>>(Wqkv, WqkvT, C_, TC3);
    transpose_cast<<<dim3(C_ / 32, C_ / 32), dim3(256), 0, stream>>>(Wproj, WprojT, C_, C_);
    // QKV projection (bf16 out)
    gemm_bt_bias<false><<<dim3(M_ / 128, TC3 / 128), dim3(256), 0, stream>>>(xb, WqkvT, bqkv, qkv, M_, TC3, C_);
    // causal flash attention
    attn_kernel<<<dim3(T_ / 64, B_ * H_), dim3(256), 0, stream>>>(qkv, yat);
    // output projection (f32 out)
    gemm_bt_bias<true><<<dim3(M_ / 128, C_ / 128), dim3(256), 0, stream>>>(yat, WprojT, bproj, out, M_, C_, C_);
}

// Round 3
// 321.425 us; speedup vs baseline: 1.2876x; 1.2876x over previous
//
#include <hip/hip_runtime.h>
#include <hip/hip_bf16.h>
#include <cstdint>

#define B_   4
#define T_   2048
#define C_   1024
#define H_   16
#define D_   64
#define TC3  3072
#define M_   (B_ * T_)   // 8192

typedef short  bf16x8 __attribute__((ext_vector_type(8)));
typedef float  f32x4  __attribute__((ext_vector_type(4)));

#define AS1(p) ((const __attribute__((address_space(1))) void*)(p))
#define AS3(p) ((__attribute__((address_space(3))) void*)(p))

__device__ inline unsigned short f2bf(float f) {
    union { float f; unsigned int i; } x; x.f = f;
    return (unsigned short)((x.i + 0x7fffu + ((x.i >> 16) & 1u)) >> 16);
}

// ---------------- cast f32 -> bf16, 8 elements/thread ----------------
__global__ void cast_f32_bf16(const float* __restrict__ in,
                              unsigned short* __restrict__ out) {
    const size_t i = ((size_t)blockIdx.x * blockDim.x + threadIdx.x) * 8;
    f32x4 a = *(const f32x4*)(in + i);
    f32x4 b = *(const f32x4*)(in + i + 4);
    bf16x8 o;
#pragma unroll
    for (int j = 0; j < 4; ++j) { o[j] = (short)f2bf(a[j]); o[4 + j] = (short)f2bf(b[j]); }
    *(bf16x8*)(out + i) = o;
}

// ---------------- transpose + cast: in[R][C] f32 -> out[C][R] bf16 ----------------
__global__ void transpose_cast(const float* __restrict__ in,
                               unsigned short* __restrict__ out, int R, int C) {
    __shared__ unsigned short tile[32][33];
    const int bc = blockIdx.x * 32, br = blockIdx.y * 32;
    const int tx = threadIdx.x & 31, ty = threadIdx.x >> 5;
#pragma unroll
    for (int i = 0; i < 4; ++i) {
        int r = ty + i * 8;
        tile[r][tx] = f2bf(in[(size_t)(br + r) * C + bc + tx]);
    }
    __syncthreads();
#pragma unroll
    for (int i = 0; i < 4; ++i) {
        int r = ty + i * 8;
        out[(size_t)(bc + r) * R + br + tx] = tile[tx][r];
    }
}

// ------------- GEMM: C[M][N] = A[M][K] * Bt[N][K]^T + bias[N] (bf16 in, f32 acc) -------------
template <bool OUTF32>
__global__ __launch_bounds__(256, 2) void gemm_bt_bias(
    const unsigned short* __restrict__ A, const unsigned short* __restrict__ Bt,
    const float* __restrict__ bias, void* __restrict__ Cout,
    int M, int N, int K) {
    __shared__ unsigned short As[128 * 32];
    __shared__ unsigned short Bs[128 * 32];
    const int tid = threadIdx.x;
    const int wave = tid >> 6, lane = tid & 63;
    const int m0 = blockIdx.x * 128, n0 = blockIdx.y * 128;
    const int wr = (wave >> 1) * 64, wc = (wave & 1) * 64;

    f32x4 acc[4][4] = {};

    const int srow = (lane >> 2);
    const int scol = (lane & 3) * 8;

    for (int k0 = 0; k0 < K; k0 += 32) {
#pragma unroll
        for (int j = 0; j < 2; ++j) {
            const int chunk = wave * 2 + j;
            const int row = chunk * 16 + srow;
            __builtin_amdgcn_global_load_lds(
                AS1(A + (size_t)(m0 + row) * K + k0 + scol),
                AS3(As + chunk * 512), 16, 0, 0);
            __builtin_amdgcn_global_load_lds(
                AS1(Bt + (size_t)(n0 + row) * K + k0 + scol),
                AS3(Bs + chunk * 512), 16, 0, 0);
        }
        __syncthreads();
        bf16x8 a[4], b[4];
#pragma unroll
        for (int i = 0; i < 4; ++i)
            a[i] = *(const bf16x8*)&As[(wr + i * 16 + (lane & 15)) * 32 + (lane >> 4) * 8];
#pragma unroll
        for (int i = 0; i < 4; ++i)
            b[i] = *(const bf16x8*)&Bs[(wc + i * 16 + (lane & 15)) * 32 + (lane >> 4) * 8];
        __builtin_amdgcn_s_setprio(1);
#pragma unroll
        for (int i = 0; i < 4; ++i)
#pragma unroll
            for (int j = 0; j < 4; ++j)
                acc[i][j] = __builtin_amdgcn_mfma_f32_16x16x32_bf16(a[i], b[j], acc[i][j], 0, 0, 0);
        __builtin_amdgcn_s_setprio(0);
        __syncthreads();
    }

#pragma unroll
    for (int i = 0; i < 4; ++i) {
        const int rowb = m0 + wr + i * 16 + (lane >> 4) * 4;
#pragma unroll
        for (int j = 0; j < 4; ++j) {
            const int col = n0 + wc + j * 16 + (lane & 15);
            const float bv = bias[col];
#pragma unroll
            for (int r = 0; r < 4; ++r) {
                const float v = acc[i][j][r] + bv;
                if (OUTF32)
                    ((float*)Cout)[(size_t)(rowb + r) * N + col] = v;
                else
                    ((unsigned short*)Cout)[(size_t)(rowb + r) * N + col] = f2bf(v);
            }
        }
    }
}

// ------------- causal flash attention -------------
// grid: (T/128, B*H). 4 waves, each owns 32 q-rows (2 m-frags). KVBLK=64.
// Vt is XOR-swizzled: element (d,k) stored at Vt[d][k ^ (8*(d>>3))].
__global__ __launch_bounds__(256, 2) void attn_kernel(
    const unsigned short* __restrict__ QKV, unsigned short* __restrict__ Y) {
    __shared__ unsigned short Kl[64][72];
    __shared__ unsigned short Vt[64][72];
    __shared__ unsigned short Pl[4][32][72];

    const int tid = threadIdx.x, wave = tid >> 6, lane = tid & 63;
    const int tq = (int)gridDim.x - 1 - (int)blockIdx.x;   // heavy blocks first
    const int qb = tq * 128;
    const int bh = blockIdx.y;
    const int b = bh >> 4, h = bh & 15;
    const size_t rowbase = (size_t)b * T_ * TC3;
    const int q0 = qb + wave * 32;
    const int l15 = lane & 15, lhi = lane >> 4;

    // Q fragments: [m-frag][k-half]; row = l15, k = lhi*8 + j (+32 for half 1)
    bf16x8 qf[2][2];
#pragma unroll
    for (int mi = 0; mi < 2; ++mi) {
        const unsigned short* p =
            QKV + rowbase + (size_t)(q0 + mi * 16 + l15) * TC3 + h * 64 + lhi * 8;
        qf[mi][0] = *(const bf16x8*)p;
        qf[mi][1] = *(const bf16x8*)(p + 32);
    }

    float m_run[2][4], l_run[2][4];
    f32x4 o[2][4] = {};
#pragma unroll
    for (int mi = 0; mi < 2; ++mi)
#pragma unroll
        for (int r = 0; r < 4; ++r) { m_run[mi][r] = -1e30f; l_run[mi][r] = 0.f; }

    const int ntiles = 2 * tq + 2;
    for (int t = 0; t < ntiles; ++t) {
        const int kv0 = t * 64;
        __syncthreads();   // previous tile's reads done before restaging
        // stage K (row-major, padded) and V (transposed + XOR-swizzled)
#pragma unroll
        for (int it = 0; it < 2; ++it) {
            const int i = tid + it * 256;
            const int row = i >> 3, seg = i & 7;
            const unsigned short* src =
                QKV + rowbase + (size_t)(kv0 + row) * TC3 + C_ + h * 64 + seg * 8;
            *(bf16x8*)&Kl[row][seg * 8] = *(const bf16x8*)src;
            bf16x8 v = *(const bf16x8*)(src + C_);
            const int swz = row ^ (seg << 3);     // d>>3 == seg for this chunk
#pragma unroll
            for (int jj = 0; jj < 8; ++jj)
                Vt[seg * 8 + jj][swz] = (unsigned short)v[jj];
        }
        __syncthreads();

        // S = Q K^T
        f32x4 s[2][4];
        __builtin_amdgcn_s_setprio(1);
#pragma unroll
        for (int kt = 0; kt < 4; ++kt) {
            bf16x8 kf0 = *(const bf16x8*)&Kl[kt * 16 + l15][lhi * 8];
            bf16x8 kf1 = *(const bf16x8*)&Kl[kt * 16 + l15][32 + lhi * 8];
#pragma unroll
            for (int mi = 0; mi < 2; ++mi) {
                f32x4 acc = {};
                acc = __builtin_amdgcn_mfma_f32_16x16x32_bf16(qf[mi][0], kf0, acc, 0, 0, 0);
                acc = __builtin_amdgcn_mfma_f32_16x16x32_bf16(qf[mi][1], kf1, acc, 0, 0, 0);
                s[mi][kt] = acc;
            }
        }
        __builtin_amdgcn_s_setprio(0);

        // scale + causal mask + online softmax (per m-frag)
#pragma unroll
        for (int mi = 0; mi < 2; ++mi) {
#pragma unroll
            for (int kt = 0; kt < 4; ++kt) {
                const int kcol = kv0 + kt * 16 + l15;
#pragma unroll
                for (int r = 0; r < 4; ++r) {
                    const int q = q0 + mi * 16 + lhi * 4 + r;
                    const float v = s[mi][kt][r] * 0.125f;
                    s[mi][kt][r] = (kcol <= q) ? v : -1e30f;
                }
            }
            float tmax[4];
#pragma unroll
            for (int r = 0; r < 4; ++r)
                tmax[r] = fmaxf(fmaxf(s[mi][0][r], s[mi][1][r]),
                                fmaxf(s[mi][2][r], s[mi][3][r]));
#pragma unroll
            for (int msk = 1; msk < 16; msk <<= 1)
#pragma unroll
                for (int r = 0; r < 4; ++r)
                    tmax[r] = fmaxf(tmax[r], __shfl_xor(tmax[r], msk, 64));

            float mnew[4], corr[4];
#pragma unroll
            for (int r = 0; r < 4; ++r) {
                mnew[r] = fmaxf(m_run[mi][r], tmax[r]);
                corr[r] = __expf(m_run[mi][r] - mnew[r]);
            }
            float tsum[4] = {0.f, 0.f, 0.f, 0.f};
#pragma unroll
            for (int kt = 0; kt < 4; ++kt)
#pragma unroll
                for (int r = 0; r < 4; ++r) {
                    const float p = __expf(s[mi][kt][r] - mnew[r]);
                    s[mi][kt][r] = p;
                    tsum[r] += p;
                }
#pragma unroll
            for (int msk = 1; msk < 16; msk <<= 1)
#pragma unroll
                for (int r = 0; r < 4; ++r)
                    tsum[r] += __shfl_xor(tsum[r], msk, 64);
#pragma unroll
            for (int r = 0; r < 4; ++r) {
                l_run[mi][r] = l_run[mi][r] * corr[r] + tsum[r];
                m_run[mi][r] = mnew[r];
            }
#pragma unroll
            for (int dt = 0; dt < 4; ++dt)
#pragma unroll
                for (int r = 0; r < 4; ++r) o[mi][dt][r] *= corr[r];

            // write P (bf16) for A-fragment relayout
#pragma unroll
            for (int kt = 0; kt < 4; ++kt)
#pragma unroll
                for (int r = 0; r < 4; ++r)
                    Pl[wave][mi * 16 + lhi * 4 + r][kt * 16 + l15] = f2bf(s[mi][kt][r]);
        }
        __syncthreads();   // Pl is per-wave; barrier also separates Vt reads below from next staging

        // PV: O += P * V
        bf16x8 pf[2][2];
#pragma unroll
        for (int mi = 0; mi < 2; ++mi) {
            pf[mi][0] = *(const bf16x8*)&Pl[wave][mi * 16 + l15][lhi * 8];
            pf[mi][1] = *(const bf16x8*)&Pl[wave][mi * 16 + l15][32 + lhi * 8];
        }
        __builtin_amdgcn_s_setprio(1);
#pragma unroll
        for (int dt = 0; dt < 4; ++dt) {
            const int d = dt * 16 + l15;
            const int xs = (d >> 3) << 3;
            bf16x8 vf0 = *(const bf16x8*)&Vt[d][(lhi * 8) ^ xs];
            bf16x8 vf1 = *(const bf16x8*)&Vt[d][(32 + lhi * 8) ^ xs];
#pragma unroll
            for (int mi = 0; mi < 2; ++mi) {
                o[mi][dt] = __builtin_amdgcn_mfma_f32_16x16x32_bf16(pf[mi][0], vf0, o[mi][dt], 0, 0, 0);
                o[mi][dt] = __builtin_amdgcn_mfma_f32_16x16x32_bf16(pf[mi][1], vf1, o[mi][dt], 0, 0, 0);
            }
        }
        __builtin_amdgcn_s_setprio(0);
    }

    // epilogue
#pragma unroll
    for (int mi = 0; mi < 2; ++mi)
#pragma unroll
        for (int dt = 0; dt < 4; ++dt)
#pragma unroll
            for (int r = 0; r < 4; ++r) {
                const int q = q0 + mi * 16 + lhi * 4 + r;
                const int d = dt * 16 + l15;
                Y[((size_t)b * T_ + q) * C_ + h * 64 + d] = f2bf(o[mi][dt][r] / l_run[mi][r]);
            }
}

extern "C" void kernel_launch(void* const* d_in, const int* in_sizes, int n_in,
                              void* d_out, int out_size, void* d_ws, size_t ws_size,
                              hipStream_t stream) {
    const float* x     = (const float*)d_in[0];
    const float* Wqkv  = (const float*)d_in[1];
    const float* bqkv  = (const float*)d_in[2];
    const float* Wproj = (const float*)d_in[3];
    const float* bproj = (const float*)d_in[4];
    float* out = (float*)d_out;

    char* ws = (char*)d_ws;
    unsigned short* qkv    = (unsigned short*)(ws);                          // 8192x3072 bf16
    unsigned short* yat    = (unsigned short*)(ws + 50331648);               // 8192x1024 bf16
    unsigned short* WqkvT  = (unsigned short*)(ws + 67108864);               // 3072x1024 bf16
    unsigned short* WprojT = (unsigned short*)(ws + 73400320);               // 1024x1024 bf16
    unsigned short* xb     = (unsigned short*)(ws + 75497472);               // 8192x1024 bf16

    cast_f32_bf16<<<dim3((M_ * C_) / (256 * 8)), dim3(256), 0, stream>>>(x, xb);
    transpose_cast<<<dim3(TC3 / 32, C_ / 32), dim3(256), 0, stream>>>(Wqkv, WqkvT, C_, TC3);
    transpose_cast<<<dim3(C_ / 32, C_ / 32), dim3(256), 0, stream>>>(Wproj, WprojT, C_, C_);
    gemm_bt_bias<false><<<dim3(M_ / 128, TC3 / 128), dim3(256), 0, stream>>>(xb, WqkvT, bqkv, qkv, M_, TC3, C_);
    attn_kernel<<<dim3(T_ / 128, B_ * H_), dim3(256), 0, stream>>>(qkv, yat);
    gemm_bt_bias<true><<<dim3(M_ / 128, C_ / 128), dim3(256), 0, stream>>>(yat, WprojT, bproj, out, M_, C_, C_);
}

// Round 4
// 225.185 us; speedup vs baseline: 1.8379x; 1.4274x over previous
//
#include <hip/hip_runtime.h>
#include <hip/hip_bf16.h>
#include <cstdint>

#define B_   4
#define T_   2048
#define C_   1024
#define H_   16
#define D_   64
#define TC3  3072
#define M_   (B_ * T_)   // 8192

typedef short  bf16x8 __attribute__((ext_vector_type(8)));
typedef float  f32x4  __attribute__((ext_vector_type(4)));

#define AS1(p) ((const __attribute__((address_space(1))) void*)(p))
#define AS3(p) ((__attribute__((address_space(3))) void*)(p))

__device__ inline unsigned short f2bf(float f) {
    union { float f; unsigned int i; } x; x.f = f;
    return (unsigned short)((x.i + 0x7fffu + ((x.i >> 16) & 1u)) >> 16);
}

// ---------------- cast f32 -> bf16, 8 elements/thread ----------------
__global__ void cast_f32_bf16(const float* __restrict__ in,
                              unsigned short* __restrict__ out) {
    const size_t i = ((size_t)blockIdx.x * blockDim.x + threadIdx.x) * 8;
    f32x4 a = *(const f32x4*)(in + i);
    f32x4 b = *(const f32x4*)(in + i + 4);
    bf16x8 o;
#pragma unroll
    for (int j = 0; j < 4; ++j) { o[j] = (short)f2bf(a[j]); o[4 + j] = (short)f2bf(b[j]); }
    *(bf16x8*)(out + i) = o;
}

// ---------------- transpose + cast: in[R][C] f32 -> out[C][R] bf16 ----------------
__global__ void transpose_cast(const float* __restrict__ in,
                               unsigned short* __restrict__ out, int R, int C) {
    __shared__ unsigned short tile[32][33];
    const int bc = blockIdx.x * 32, br = blockIdx.y * 32;
    const int tx = threadIdx.x & 31, ty = threadIdx.x >> 5;
#pragma unroll
    for (int i = 0; i < 4; ++i) {
        int r = ty + i * 8;
        tile[r][tx] = f2bf(in[(size_t)(br + r) * C + bc + tx]);
    }
    __syncthreads();
#pragma unroll
    for (int i = 0; i < 4; ++i) {
        int r = ty + i * 8;
        out[(size_t)(bc + r) * R + br + tx] = tile[tx][r];
    }
}

// ------------- GEMM: C[M][N] = A[M][K] * Bt[N][K]^T + bias[N] (bf16 in, f32 acc) -------------
template <bool OUTF32>
__global__ __launch_bounds__(256, 2) void gemm_bt_bias(
    const unsigned short* __restrict__ A, const unsigned short* __restrict__ Bt,
    const float* __restrict__ bias, void* __restrict__ Cout,
    int M, int N, int K) {
    __shared__ unsigned short As[128 * 32];
    __shared__ unsigned short Bs[128 * 32];
    const int tid = threadIdx.x;
    const int wave = tid >> 6, lane = tid & 63;
    const int m0 = blockIdx.x * 128, n0 = blockIdx.y * 128;
    const int wr = (wave >> 1) * 64, wc = (wave & 1) * 64;

    f32x4 acc[4][4] = {};

    const int srow = (lane >> 2);
    const int scol = (lane & 3) * 8;

    for (int k0 = 0; k0 < K; k0 += 32) {
#pragma unroll
        for (int j = 0; j < 2; ++j) {
            const int chunk = wave * 2 + j;
            const int row = chunk * 16 + srow;
            __builtin_amdgcn_global_load_lds(
                AS1(A + (size_t)(m0 + row) * K + k0 + scol),
                AS3(As + chunk * 512), 16, 0, 0);
            __builtin_amdgcn_global_load_lds(
                AS1(Bt + (size_t)(n0 + row) * K + k0 + scol),
                AS3(Bs + chunk * 512), 16, 0, 0);
        }
        __syncthreads();
        bf16x8 a[4], b[4];
#pragma unroll
        for (int i = 0; i < 4; ++i)
            a[i] = *(const bf16x8*)&As[(wr + i * 16 + (lane & 15)) * 32 + (lane >> 4) * 8];
#pragma unroll
        for (int i = 0; i < 4; ++i)
            b[i] = *(const bf16x8*)&Bs[(wc + i * 16 + (lane & 15)) * 32 + (lane >> 4) * 8];
        __builtin_amdgcn_s_setprio(1);
#pragma unroll
        for (int i = 0; i < 4; ++i)
#pragma unroll
            for (int j = 0; j < 4; ++j)
                acc[i][j] = __builtin_amdgcn_mfma_f32_16x16x32_bf16(a[i], b[j], acc[i][j], 0, 0, 0);
        __builtin_amdgcn_s_setprio(0);
        __syncthreads();
    }

#pragma unroll
    for (int i = 0; i < 4; ++i) {
        const int rowb = m0 + wr + i * 16 + (lane >> 4) * 4;
#pragma unroll
        for (int j = 0; j < 4; ++j) {
            const int col = n0 + wc + j * 16 + (lane & 15);
            const float bv = bias[col];
#pragma unroll
            for (int r = 0; r < 4; ++r) {
                const float v = acc[i][j][r] + bv;
                if (OUTF32)
                    ((float*)Cout)[(size_t)(rowb + r) * N + col] = v;
                else
                    ((unsigned short*)Cout)[(size_t)(rowb + r) * N + col] = f2bf(v);
            }
        }
    }
}

// ------------- causal flash attention -------------
// grid: (B*H, 8). Block (bh, pr) processes strips tq=pr and tq=15-pr (QBLK=128
// each) -> uniform 34 tiles/block.  4 waves x 32 q-rows.  KVBLK=64.
// K in LDS [64][72] padded; V pair-packed u32 [d][k2^(seg<<2)] (2-way-free
// writes, contiguous b128 reads).  T14 async staging: load t+1 early, write
// after the tail barrier.  2 barriers/tile.
__global__ __launch_bounds__(256, 2) void attn_kernel(
    const unsigned short* __restrict__ QKV, unsigned short* __restrict__ Y) {
    __shared__ unsigned short Kl[64][72];
    __shared__ unsigned int   Vt32[64][36];
    __shared__ unsigned short Pl[4][32][72];

    const int tid = threadIdx.x, wave = tid >> 6, lane = tid & 63;
    const int bh = blockIdx.x;           // XCD = bh & 7 -> pair-blocks share L2
    const int pr = blockIdx.y;           // 0..7
    const int b = bh >> 4, h = bh & 15;
    const size_t rowbase = (size_t)b * T_ * TC3;
    const int l15 = lane & 15, lhi = lane >> 4;
    const int sk2 = tid >> 3;            // 0..31 (k-pair)
    const int sseg = tid & 7;            // 0..7  (d-segment)

    for (int sp = 0; sp < 2; ++sp) {
        const int tq = sp ? (15 - pr) : pr;
        const int qb = tq * 128;
        const int q0 = qb + wave * 32;
        const int ntiles = 2 * tq + 2;

        // Q fragments for this strip
        bf16x8 qf[2][2];
#pragma unroll
        for (int mi = 0; mi < 2; ++mi) {
            const unsigned short* p =
                QKV + rowbase + (size_t)(q0 + mi * 16 + l15) * TC3 + h * 64 + lhi * 8;
            qf[mi][0] = *(const bf16x8*)p;
            qf[mi][1] = *(const bf16x8*)(p + 32);
        }

        float m_run[2][4], l_run[2][4];
        f32x4 o[2][4] = {};
#pragma unroll
        for (int mi = 0; mi < 2; ++mi)
#pragma unroll
            for (int r = 0; r < 4; ++r) { m_run[mi][r] = -1e30f; l_run[mi][r] = 0.f; }

        __syncthreads();   // previous strip's LDS reads complete
        // prologue: stage tile 0
        {
            const unsigned short* src =
                QKV + rowbase + (size_t)(2 * sk2) * TC3 + C_ + h * 64 + sseg * 8;
            bf16x8 ka = *(const bf16x8*)src;
            bf16x8 kb = *(const bf16x8*)(src + TC3);
            bf16x8 va = *(const bf16x8*)(src + C_);
            bf16x8 vb = *(const bf16x8*)(src + C_ + TC3);
            *(bf16x8*)&Kl[2 * sk2][sseg * 8] = ka;
            *(bf16x8*)&Kl[2 * sk2 + 1][sseg * 8] = kb;
            const int kx = sk2 ^ (sseg << 2);
#pragma unroll
            for (int j = 0; j < 8; ++j)
                Vt32[sseg * 8 + j][kx] =
                    (unsigned int)(unsigned short)va[j] |
                    ((unsigned int)(unsigned short)vb[j] << 16);
        }

        for (int t = 0; t < ntiles; ++t) {
            const int kv0 = t * 64;
            __syncthreads();   // staged tile t visible

            // T14: issue next tile's global loads now, write after tail barrier
            bf16x8 pka, pkb, pva, pvb;
            const bool pf_valid = (t + 1 < ntiles);
            if (pf_valid) {
                const unsigned short* src =
                    QKV + rowbase + (size_t)(kv0 + 64 + 2 * sk2) * TC3 + C_ + h * 64 + sseg * 8;
                pka = *(const bf16x8*)src;
                pkb = *(const bf16x8*)(src + TC3);
                pva = *(const bf16x8*)(src + C_);
                pvb = *(const bf16x8*)(src + C_ + TC3);
            }

            if (q0 + 31 >= kv0) {   // wave-tile not fully masked
                // S = Q K^T
                f32x4 s[2][4];
                __builtin_amdgcn_s_setprio(1);
#pragma unroll
                for (int kt = 0; kt < 4; ++kt) {
                    bf16x8 kf0 = *(const bf16x8*)&Kl[kt * 16 + l15][lhi * 8];
                    bf16x8 kf1 = *(const bf16x8*)&Kl[kt * 16 + l15][32 + lhi * 8];
#pragma unroll
                    for (int mi = 0; mi < 2; ++mi) {
                        f32x4 acc = {};
                        acc = __builtin_amdgcn_mfma_f32_16x16x32_bf16(qf[mi][0], kf0, acc, 0, 0, 0);
                        acc = __builtin_amdgcn_mfma_f32_16x16x32_bf16(qf[mi][1], kf1, acc, 0, 0, 0);
                        s[mi][kt] = acc;
                    }
                }
                __builtin_amdgcn_s_setprio(0);

                const bool needmask = (kv0 + 63 > q0);
#pragma unroll
                for (int mi = 0; mi < 2; ++mi) {
                    if (needmask) {
#pragma unroll
                        for (int kt = 0; kt < 4; ++kt) {
                            const int kcol = kv0 + kt * 16 + l15;
#pragma unroll
                            for (int r = 0; r < 4; ++r) {
                                const int q = q0 + mi * 16 + lhi * 4 + r;
                                const float v = s[mi][kt][r] * 0.125f;
                                s[mi][kt][r] = (kcol <= q) ? v : -1e30f;
                            }
                        }
                    } else {
#pragma unroll
                        for (int kt = 0; kt < 4; ++kt)
#pragma unroll
                            for (int r = 0; r < 4; ++r)
                                s[mi][kt][r] *= 0.125f;
                    }
                    float tmax[4];
#pragma unroll
                    for (int r = 0; r < 4; ++r)
                        tmax[r] = fmaxf(fmaxf(s[mi][0][r], s[mi][1][r]),
                                        fmaxf(s[mi][2][r], s[mi][3][r]));
#pragma unroll
                    for (int msk = 1; msk < 16; msk <<= 1)
#pragma unroll
                        for (int r = 0; r < 4; ++r)
                            tmax[r] = fmaxf(tmax[r], __shfl_xor(tmax[r], msk, 64));

                    // defer-max (T13): only rescale when max grew past threshold
                    bool exc = false;
#pragma unroll
                    for (int r = 0; r < 4; ++r)
                        exc = exc || (tmax[r] > m_run[mi][r] + 8.0f);
                    if (__any(exc)) {
#pragma unroll
                        for (int r = 0; r < 4; ++r) {
                            const float mnew = fmaxf(m_run[mi][r], tmax[r]);
                            const float corr = __expf(m_run[mi][r] - mnew);
                            m_run[mi][r] = mnew;
                            l_run[mi][r] *= corr;
#pragma unroll
                            for (int dt = 0; dt < 4; ++dt) o[mi][dt][r] *= corr;
                        }
                    }
                    float tsum[4] = {0.f, 0.f, 0.f, 0.f};
#pragma unroll
                    for (int kt = 0; kt < 4; ++kt)
#pragma unroll
                        for (int r = 0; r < 4; ++r) {
                            const float p = __expf(s[mi][kt][r] - m_run[mi][r]);
                            s[mi][kt][r] = p;
                            tsum[r] += p;
                        }
#pragma unroll
                    for (int msk = 1; msk < 16; msk <<= 1)
#pragma unroll
                        for (int r = 0; r < 4; ++r)
                            tsum[r] += __shfl_xor(tsum[r], msk, 64);
#pragma unroll
                    for (int r = 0; r < 4; ++r) l_run[mi][r] += tsum[r];

                    // P relayout via per-wave LDS (no block barrier needed)
#pragma unroll
                    for (int kt = 0; kt < 4; ++kt)
#pragma unroll
                        for (int r = 0; r < 4; ++r)
                            Pl[wave][mi * 16 + lhi * 4 + r][kt * 16 + l15] = f2bf(s[mi][kt][r]);
                }

                // PV: O += P * V
                bf16x8 pf[2][2];
#pragma unroll
                for (int mi = 0; mi < 2; ++mi) {
                    pf[mi][0] = *(const bf16x8*)&Pl[wave][mi * 16 + l15][lhi * 8];
                    pf[mi][1] = *(const bf16x8*)&Pl[wave][mi * 16 + l15][32 + lhi * 8];
                }
                __builtin_amdgcn_s_setprio(1);
#pragma unroll
                for (int dt = 0; dt < 4; ++dt) {
                    const int d = dt * 16 + l15;
                    const int s4 = (d >> 3) << 2;
                    bf16x8 vf0 = *(const bf16x8*)&Vt32[d][(lhi * 4) ^ s4];
                    bf16x8 vf1 = *(const bf16x8*)&Vt32[d][(16 + lhi * 4) ^ s4];
#pragma unroll
                    for (int mi = 0; mi < 2; ++mi) {
                        o[mi][dt] = __builtin_amdgcn_mfma_f32_16x16x32_bf16(pf[mi][0], vf0, o[mi][dt], 0, 0, 0);
                        o[mi][dt] = __builtin_amdgcn_mfma_f32_16x16x32_bf16(pf[mi][1], vf1, o[mi][dt], 0, 0, 0);
                    }
                }
                __builtin_amdgcn_s_setprio(0);
            }

            __syncthreads();   // all reads of tile t complete
            if (pf_valid) {
                *(bf16x8*)&Kl[2 * sk2][sseg * 8] = pka;
                *(bf16x8*)&Kl[2 * sk2 + 1][sseg * 8] = pkb;
                const int kx = sk2 ^ (sseg << 2);
#pragma unroll
                for (int j = 0; j < 8; ++j)
                    Vt32[sseg * 8 + j][kx] =
                        (unsigned int)(unsigned short)pva[j] |
                        ((unsigned int)(unsigned short)pvb[j] << 16);
            }
        }

        // epilogue for this strip
#pragma unroll
        for (int mi = 0; mi < 2; ++mi)
#pragma unroll
            for (int dt = 0; dt < 4; ++dt)
#pragma unroll
                for (int r = 0; r < 4; ++r) {
                    const int q = q0 + mi * 16 + lhi * 4 + r;
                    const int d = dt * 16 + l15;
                    Y[((size_t)b * T_ + q) * C_ + h * 64 + d] = f2bf(o[mi][dt][r] / l_run[mi][r]);
                }
    }
}

extern "C" void kernel_launch(void* const* d_in, const int* in_sizes, int n_in,
                              void* d_out, int out_size, void* d_ws, size_t ws_size,
                              hipStream_t stream) {
    const float* x     = (const float*)d_in[0];
    const float* Wqkv  = (const float*)d_in[1];
    const float* bqkv  = (const float*)d_in[2];
    const float* Wproj = (const float*)d_in[3];
    const float* bproj = (const float*)d_in[4];
    float* out = (float*)d_out;

    char* ws = (char*)d_ws;
    unsigned short* qkv    = (unsigned short*)(ws);                          // 8192x3072 bf16
    unsigned short* yat    = (unsigned short*)(ws + 50331648);               // 8192x1024 bf16
    unsigned short* WqkvT  = (unsigned short*)(ws + 67108864);               // 3072x1024 bf16
    unsigned short* WprojT = (unsigned short*)(ws + 73400320);               // 1024x1024 bf16
    unsigned short* xb     = (unsigned short*)(ws + 75497472);               // 8192x1024 bf16

    cast_f32_bf16<<<dim3((M_ * C_) / (256 * 8)), dim3(256), 0, stream>>>(x, xb);
    transpose_cast<<<dim3(TC3 / 32, C_ / 32), dim3(256), 0, stream>>>(Wqkv, WqkvT, C_, TC3);
    transpose_cast<<<dim3(C_ / 32, C_ / 32), dim3(256), 0, stream>>>(Wproj, WprojT, C_, C_);
    gemm_bt_bias<false><<<dim3(M_ / 128, TC3 / 128), dim3(256), 0, stream>>>(xb, WqkvT, bqkv, qkv, M_, TC3, C_);
    attn_kernel<<<dim3(B_ * H_, 8), dim3(256), 0, stream>>>(qkv, yat);
    gemm_bt_bias<true><<<dim3(M_ / 128, C_ / 128), dim3(256), 0, stream>>>(yat, WprojT, bproj, out, M_, C_, C_);
}